// Round 1
// baseline (1403.644 us; speedup 1.0000x reference)
//
#include <hip/hip_runtime.h>

// VecInt (scaling-and-squaring) for vel field (2,160,192,160,3) fp32.
// disp = vel / 2^7; repeat 7x: disp = disp + trilinear_sample(disp, grid + disp).
//
// v2 changes vs. baseline (749 us):
//  - 4 voxels per thread along x: 32 independent dwordx3 gathers per thread
//    (Little's law: baseline was concurrency-limited at 2.95 TB/s with only
//    ~9 small loads in flight per wave; VGPR=20 left huge headroom).
//  - float4-vectorized own-disp load (3x16B) and result store (3x16B).
//  - scale_k folded into the first squaring step (reads vel, scales own value
//    and folds 1/128 into the trilinear weights) -> one full 236MB pass saved.
//  - Launch order: fused step writes d_out, then 6 ping-pong steps end in d_out.

namespace {

constexpr int Dd = 160, Hh = 192, Ww = 160, Bb = 2;
constexpr int HW   = Hh * Ww;        // 30720
constexpr int VOX  = Dd * HW;        // 4,915,200
constexpr int NTOT = Bb * VOX;       // 9,830,400
constexpr int NT4  = NTOT / 4;       // 2,457,600 threads (4 voxels each)
constexpr int W4   = Ww / 4;         // 40
constexpr int HW4  = HW / 4;         // 7680
constexpr int VOX4 = VOX / 4;        // 1,228,800 (divisible by 256 -> b wave-uniform)

template <bool SCALE>
__global__ __launch_bounds__(256) void step4_k(const float* __restrict__ src,
                                               float* __restrict__ out) {
    int t = blockIdx.x * 256 + threadIdx.x;
    if (t >= NT4) return;  // grid is exact (9600*256), defensive only

    int b = (t >= VOX4) ? 1 : 0;     // batch split; uniform within a block
    int v = t - b * VOX4;
    int z = v / HW4;
    int rem = v - z * HW4;
    int y = rem / W4;
    int x = (rem - y * W4) * 4;      // first of 4 consecutive x voxels

    const float* __restrict__ vol = src + b * (VOX * 3);
    int base = t * 12;               // float offset of voxel0 channel0 (fits int)

    // own displacements for 4 voxels: 12 contiguous floats, 48B aligned to 16
    const float4* srcv = reinterpret_cast<const float4*>(src + base);
    float4 own0 = srcv[0], own1 = srcv[1], own2 = srcv[2];

    float dzv[4] = {own0.x, own0.w, own1.z, own2.y};
    float dyv[4] = {own0.y, own1.x, own1.w, own2.z};
    float dxv[4] = {own0.z, own1.y, own2.x, own2.w};

    constexpr float s = SCALE ? (1.0f / 128.0f) : 1.0f;

    float r0[4], r1[4], r2[4];

#pragma unroll
    for (int j = 0; j < 4; ++j) {
        float d0 = dzv[j] * s;   // z-displacement ('ij': channel 0 = D axis)
        float d1 = dyv[j] * s;
        float d2 = dxv[j] * s;

        float lz = fminf(fmaxf((float)z + d0, 0.0f), (float)(Dd - 1));
        float ly = fminf(fmaxf((float)y + d1, 0.0f), (float)(Hh - 1));
        float lx = fminf(fmaxf((float)(x + j) + d2, 0.0f), (float)(Ww - 1));

        float fz = floorf(lz), fy = floorf(ly), fx = floorf(lx);
        int z0 = (int)fz, y0 = (int)fy, x0 = (int)fx;
        int z1 = min(z0 + 1, Dd - 1);
        int y1 = min(y0 + 1, Hh - 1);
        int x1 = min(x0 + 1, Ww - 1);
        float tz = lz - fz, ty = ly - fy, tx = lx - fx;
        float sz = 1.0f - tz, sy = 1.0f - ty, sx = 1.0f - tx;

        // fold the 1/128 scale of the *sampled* field into the weights
        float w000 = sz * sy * sx * s, w001 = sz * sy * tx * s;
        float w010 = sz * ty * sx * s, w011 = sz * ty * tx * s;
        float w100 = tz * sy * sx * s, w101 = tz * sy * tx * s;
        float w110 = tz * ty * sx * s, w111 = tz * ty * tx * s;

        int q00 = (z0 * Hh + y0) * Ww;
        int q01 = (z0 * Hh + y1) * Ww;
        int q10 = (z1 * Hh + y0) * Ww;
        int q11 = (z1 * Hh + y1) * Ww;
        int o000 = (q00 + x0) * 3, o001 = (q00 + x1) * 3;
        int o010 = (q01 + x0) * 3, o011 = (q01 + x1) * 3;
        int o100 = (q10 + x0) * 3, o101 = (q10 + x1) * 3;
        int o110 = (q11 + x0) * 3, o111 = (q11 + x1) * 3;

        float a0 = w000 * vol[o000 + 0] + w001 * vol[o001 + 0]
                 + w010 * vol[o010 + 0] + w011 * vol[o011 + 0]
                 + w100 * vol[o100 + 0] + w101 * vol[o101 + 0]
                 + w110 * vol[o110 + 0] + w111 * vol[o111 + 0];
        float a1 = w000 * vol[o000 + 1] + w001 * vol[o001 + 1]
                 + w010 * vol[o010 + 1] + w011 * vol[o011 + 1]
                 + w100 * vol[o100 + 1] + w101 * vol[o101 + 1]
                 + w110 * vol[o110 + 1] + w111 * vol[o111 + 1];
        float a2 = w000 * vol[o000 + 2] + w001 * vol[o001 + 2]
                 + w010 * vol[o010 + 2] + w011 * vol[o011 + 2]
                 + w100 * vol[o100 + 2] + w101 * vol[o101 + 2]
                 + w110 * vol[o110 + 2] + w111 * vol[o111 + 2];

        r0[j] = d0 + a0;
        r1[j] = d1 + a1;
        r2[j] = d2 + a2;
    }

    float4* outv = reinterpret_cast<float4*>(out + base);
    outv[0] = make_float4(r0[0], r1[0], r2[0], r0[1]);
    outv[1] = make_float4(r1[1], r2[1], r0[2], r1[2]);
    outv[2] = make_float4(r2[2], r0[3], r1[3], r2[3]);
}

}  // namespace

extern "C" void kernel_launch(void* const* d_in, const int* in_sizes, int n_in,
                              void* d_out, int out_size, void* d_ws, size_t ws_size,
                              hipStream_t stream) {
    const float* vel = (const float*)d_in[0];
    float* out = (float*)d_out;
    float* ws  = (float*)d_ws;   // needs NTOT*3*4 = ~118 MB

    int blk = 256;
    int grd = NT4 / blk;         // 9600, exact

    // Iteration 1 fused with the 1/128 scale: vel -> d_out
    step4_k<true><<<grd, blk, 0, stream>>>(vel, out);

    // Iterations 2..7, ping-pong out <-> ws; 6 (even) steps end in d_out.
    float* a = out;
    float* c = ws;
    for (int it = 1; it < 7; ++it) {
        step4_k<false><<<grd, blk, 0, stream>>>(a, c);
        float* tmp = a; a = c; c = tmp;
    }
    // a == out here: final result in d_out.
}

// Round 2
// 822.689 us; speedup vs baseline: 1.7062x; 1.7062x over previous
//
#include <hip/hip_runtime.h>

// VecInt (scaling-and-squaring) for vel field (2,160,192,160,3) fp32.
// disp = vel / 2^7; repeat 7x: disp = disp + trilinear_sample(disp, grid + disp).
//
// v3:
//  - REVERT v2's 4-voxels-along-x (FETCH 2.1x'd: per-XCD L2 span exceeded 4MiB,
//    thrashing the corner-row reuse; dur 85->231us/step).
//  - KEEP fused 1/128 scale in the first step (8 dispatches -> 7).
//  - NEW: 2 voxels/thread paired along y. The pair shares its middle corner
//    rows (6 rows/wave vs 8 for two independent voxels -> 48 B/voxel unique
//    footprint vs 52 baseline) while doubling independent gathers in flight
//    (16 dwordx3 per thread). MLP up ~2x, L2 span up only ~1.5x.

namespace {

constexpr int Dd = 160, Hh = 192, Ww = 160, Bb = 2;
constexpr int HW   = Hh * Ww;        // 30720
constexpr int VOX  = Dd * HW;        // 4,915,200
constexpr int NTOT = Bb * VOX;       // 9,830,400
constexpr int H2   = Hh / 2;         // 96
constexpr int HW2  = HW / 2;         // 15360
constexpr int VOX2 = VOX / 2;        // 2,457,600 (divisible by 256 -> b uniform/block)
constexpr int NT2  = NTOT / 2;       // 4,915,200 threads, 2 voxels each

template <bool SCALE>
__global__ __launch_bounds__(256) void step2_k(const float* __restrict__ src,
                                               float* __restrict__ out) {
    int t = blockIdx.x * 256 + threadIdx.x;
    if (t >= NT2) return;            // grid exact (19200*256), defensive only

    int b = (t >= VOX2) ? 1 : 0;     // uniform within a block
    int v = t - b * VOX2;
    int z = v / HW2;
    int rem = v - z * HW2;
    int y2 = rem / Ww;
    int x = rem - y2 * Ww;
    int y = y2 * 2;                  // this thread owns (z,y,x) and (z,y+1,x)

    const float* __restrict__ vol = src + b * (VOX * 3);
    float* __restrict__ outb = out + b * (VOX * 3);

    int i0 = ((z * Hh + y) * Ww + x) * 3;   // voxel (z, y,   x), float offset
    int i1 = i0 + Ww * 3;                   // voxel (z, y+1, x)

    constexpr float s = SCALE ? (1.0f / 128.0f) : 1.0f;

    // own displacements (coalesced dwordx3 per voxel-row)
    float dz_[2], dy_[2], dx_[2];
    dz_[0] = vol[i0 + 0]; dy_[0] = vol[i0 + 1]; dx_[0] = vol[i0 + 2];
    dz_[1] = vol[i1 + 0]; dy_[1] = vol[i1 + 1]; dx_[1] = vol[i1 + 2];

    float r0[2], r1[2], r2[2];

#pragma unroll
    for (int j = 0; j < 2; ++j) {
        float d0 = dz_[j] * s;       // 'ij' indexing: channel 0 = D(z) axis
        float d1 = dy_[j] * s;
        float d2 = dx_[j] * s;
        int yj = y + j;

        float lz = fminf(fmaxf((float)z  + d0, 0.0f), (float)(Dd - 1));
        float ly = fminf(fmaxf((float)yj + d1, 0.0f), (float)(Hh - 1));
        float lx = fminf(fmaxf((float)x  + d2, 0.0f), (float)(Ww - 1));

        float fz = floorf(lz), fy = floorf(ly), fx = floorf(lx);
        int z0 = (int)fz, y0 = (int)fy, x0 = (int)fx;
        int z1 = min(z0 + 1, Dd - 1);
        int y1 = min(y0 + 1, Hh - 1);
        int x1 = min(x0 + 1, Ww - 1);
        float tz = lz - fz, ty = ly - fy, tx = lx - fx;
        float sz = 1.0f - tz, sy = 1.0f - ty, sx = 1.0f - tx;

        // fold the 1/128 scale of the *sampled* field into the weights
        float w000 = sz * sy * sx * s, w001 = sz * sy * tx * s;
        float w010 = sz * ty * sx * s, w011 = sz * ty * tx * s;
        float w100 = tz * sy * sx * s, w101 = tz * sy * tx * s;
        float w110 = tz * ty * sx * s, w111 = tz * ty * tx * s;

        int q00 = (z0 * Hh + y0) * Ww;
        int q01 = (z0 * Hh + y1) * Ww;
        int q10 = (z1 * Hh + y0) * Ww;
        int q11 = (z1 * Hh + y1) * Ww;
        int o000 = (q00 + x0) * 3, o001 = (q00 + x1) * 3;
        int o010 = (q01 + x0) * 3, o011 = (q01 + x1) * 3;
        int o100 = (q10 + x0) * 3, o101 = (q10 + x1) * 3;
        int o110 = (q11 + x0) * 3, o111 = (q11 + x1) * 3;

        float a0 = w000 * vol[o000 + 0] + w001 * vol[o001 + 0]
                 + w010 * vol[o010 + 0] + w011 * vol[o011 + 0]
                 + w100 * vol[o100 + 0] + w101 * vol[o101 + 0]
                 + w110 * vol[o110 + 0] + w111 * vol[o111 + 0];
        float a1 = w000 * vol[o000 + 1] + w001 * vol[o001 + 1]
                 + w010 * vol[o010 + 1] + w011 * vol[o011 + 1]
                 + w100 * vol[o100 + 1] + w101 * vol[o101 + 1]
                 + w110 * vol[o110 + 1] + w111 * vol[o111 + 1];
        float a2 = w000 * vol[o000 + 2] + w001 * vol[o001 + 2]
                 + w010 * vol[o010 + 2] + w011 * vol[o011 + 2]
                 + w100 * vol[o100 + 2] + w101 * vol[o101 + 2]
                 + w110 * vol[o110 + 2] + w111 * vol[o111 + 2];

        r0[j] = d0 + a0;
        r1[j] = d1 + a1;
        r2[j] = d2 + a2;
    }

    outb[i0 + 0] = r0[0]; outb[i0 + 1] = r1[0]; outb[i0 + 2] = r2[0];
    outb[i1 + 0] = r0[1]; outb[i1 + 1] = r1[1]; outb[i1 + 2] = r2[1];
}

}  // namespace

extern "C" void kernel_launch(void* const* d_in, const int* in_sizes, int n_in,
                              void* d_out, int out_size, void* d_ws, size_t ws_size,
                              hipStream_t stream) {
    const float* vel = (const float*)d_in[0];
    float* out = (float*)d_out;
    float* ws  = (float*)d_ws;   // needs NTOT*3*4 = ~118 MB

    int blk = 256;
    int grd = NT2 / blk;         // 19200, exact

    // Iteration 1 fused with the 1/128 scale: vel -> d_out
    step2_k<true><<<grd, blk, 0, stream>>>(vel, out);

    // Iterations 2..7, ping-pong out <-> ws; 6 (even) steps end in d_out.
    float* a = out;
    float* c = ws;
    for (int it = 1; it < 7; ++it) {
        step2_k<false><<<grd, blk, 0, stream>>>(a, c);
        float* tmp = a; a = c; c = tmp;
    }
    // a == out here: final result in d_out.
}

// Round 3
// 736.381 us; speedup vs baseline: 1.9061x; 1.1172x over previous
//
#include <hip/hip_runtime.h>

// VecInt (scaling-and-squaring) for vel field (2,160,192,160,3) fp32.
// disp = vel / 2^7; repeat 7x: disp = disp + trilinear_sample(disp, grid + disp).
//
// v4:
//  - 1 voxel/thread (v2: 4/thread -> FETCH 2.1x; v3: 2/thread -> FETCH 1.46x;
//    multi-voxel threads stretch reuse distance past the L2 window — reverted).
//  - KEEP fused 1/128 scale in the first step (8 dispatches -> 7, saves a
//    full 236MB pass).
//  - NEW: 2D patch lane mapping. Block = 16x16 (y,x) tile, wave = 4y x 16x.
//    Wave gather footprint ~5.3KB vs ~11.8KB for the 256-along-x mapping,
//    so the 8 corner gathers hit L1/L2 far more often. Same instruction
//    count and coalescing class; grid (10,12,320) exact, no bounds checks.

namespace {

constexpr int Dd = 160, Hh = 192, Ww = 160, Bb = 2;
constexpr int HW  = Hh * Ww;                 // 30720
constexpr int VOX = Dd * HW;                 // 4,915,200 per batch

template <bool SCALE>
__global__ __launch_bounds__(256) void step_k(const float* __restrict__ src,
                                              float* __restrict__ out) {
    int tid = threadIdx.x;
    int x = blockIdx.x * 16 + (tid & 15);
    int y = blockIdx.y * 16 + (tid >> 4);
    int zb = blockIdx.z;                 // b*Dd + z
    int z = zb, b = 0;
    if (zb >= Dd) { b = 1; z = zb - Dd; }

    const float* __restrict__ vol = src + (long long)b * VOX * 3;

    int idx = (zb * Hh + y) * Ww + x;    // linear over both batches, < 9.9M
    int base3 = idx * 3;                 // < 29.5M, fits int

    float d0 = src[base3 + 0];           // 'ij' indexing: channel 0 = D(z) axis
    float d1 = src[base3 + 1];
    float d2 = src[base3 + 2];

    constexpr float s = SCALE ? (1.0f / 128.0f) : 1.0f;
    d0 *= s; d1 *= s; d2 *= s;

    float lz = fminf(fmaxf((float)z + d0, 0.0f), (float)(Dd - 1));
    float ly = fminf(fmaxf((float)y + d1, 0.0f), (float)(Hh - 1));
    float lx = fminf(fmaxf((float)x + d2, 0.0f), (float)(Ww - 1));

    float fz = floorf(lz), fy = floorf(ly), fx = floorf(lx);
    int z0 = (int)fz, y0 = (int)fy, x0 = (int)fx;
    int z1 = min(z0 + 1, Dd - 1);
    int y1 = min(y0 + 1, Hh - 1);
    int x1 = min(x0 + 1, Ww - 1);
    float tz = lz - fz, ty = ly - fy, tx = lx - fx;
    float sz = 1.0f - tz, sy = 1.0f - ty, sx = 1.0f - tx;

    // fold the 1/128 scale of the *sampled* field into the weights
    float w000 = sz * sy * sx * s, w001 = sz * sy * tx * s;
    float w010 = sz * ty * sx * s, w011 = sz * ty * tx * s;
    float w100 = tz * sy * sx * s, w101 = tz * sy * tx * s;
    float w110 = tz * ty * sx * s, w111 = tz * ty * tx * s;

    int r00 = (z0 * Hh + y0) * Ww;
    int r01 = (z0 * Hh + y1) * Ww;
    int r10 = (z1 * Hh + y0) * Ww;
    int r11 = (z1 * Hh + y1) * Ww;

    const float* p000 = vol + (r00 + x0) * 3;
    const float* p001 = vol + (r00 + x1) * 3;
    const float* p010 = vol + (r01 + x0) * 3;
    const float* p011 = vol + (r01 + x1) * 3;
    const float* p100 = vol + (r10 + x0) * 3;
    const float* p101 = vol + (r10 + x1) * 3;
    const float* p110 = vol + (r11 + x0) * 3;
    const float* p111 = vol + (r11 + x1) * 3;

    float a0 = w000 * p000[0] + w001 * p001[0] + w010 * p010[0] + w011 * p011[0]
             + w100 * p100[0] + w101 * p101[0] + w110 * p110[0] + w111 * p111[0];
    float a1 = w000 * p000[1] + w001 * p001[1] + w010 * p010[1] + w011 * p011[1]
             + w100 * p100[1] + w101 * p101[1] + w110 * p110[1] + w111 * p111[1];
    float a2 = w000 * p000[2] + w001 * p001[2] + w010 * p010[2] + w011 * p011[2]
             + w100 * p100[2] + w101 * p101[2] + w110 * p110[2] + w111 * p111[2];

    out[base3 + 0] = d0 + a0;
    out[base3 + 1] = d1 + a1;
    out[base3 + 2] = d2 + a2;
}

}  // namespace

extern "C" void kernel_launch(void* const* d_in, const int* in_sizes, int n_in,
                              void* d_out, int out_size, void* d_ws, size_t ws_size,
                              hipStream_t stream) {
    const float* vel = (const float*)d_in[0];
    float* out = (float*)d_out;
    float* ws  = (float*)d_ws;   // needs NTOT*3*4 = ~118 MB

    dim3 blk(256);
    dim3 grd(Ww / 16, Hh / 16, Bb * Dd);   // (10, 12, 320), exact

    // Iteration 1 fused with the 1/128 scale: vel -> d_out
    step_k<true><<<grd, blk, 0, stream>>>(vel, out);

    // Iterations 2..7, ping-pong out <-> ws; 6 (even) steps end in d_out.
    float* a = out;
    float* c = ws;
    for (int it = 1; it < 7; ++it) {
        step_k<false><<<grd, blk, 0, stream>>>(a, c);
        float* tmp = a; a = c; c = tmp;
    }
    // a == out here: final result in d_out.
}